// Round 10
// baseline (642.294 us; speedup 1.0000x reference)
//
#include <hip/hip_runtime.h>
#include <hip/hip_bf16.h>

// CxNNxNN attention. B=8, C=64, H=W=256, head=8, N=8.
// token n = (h&7)*8 + (w&7)  [64], feature d = (h>>3)*32 + (w>>3)  [1024].

typedef __attribute__((ext_vector_type(8))) short short8;  // 8 bf16 (4 VGPR)
typedef __attribute__((ext_vector_type(4))) float f4;      // MFMA acc
typedef unsigned short u16;

#define PST 72  // bf16 plane row stride (ushorts)

// ---------------- bf16 hi/lo helpers ----------------
__device__ __forceinline__ float tof(u16 u) {
  return __builtin_bit_cast(float, ((unsigned)u) << 16);
}
__device__ __forceinline__ void fsplit(float o, u16& h, u16& l) {
  unsigned u = __builtin_bit_cast(unsigned, o);
  h = (u16)(u >> 16);  // truncate; lo compensates
  float hf = __builtin_bit_cast(float, u & 0xffff0000u);
  l = (u16)(__builtin_bit_cast(unsigned, o - hf) >> 16);
}
__device__ __forceinline__ short8 ldfrag(const u16* p, int row, int ko) {
  return *(const short8*)&p[row * PST + ko];
}

// ---------------- K1/K3: pointwise GEMM on MFMA ----------------
// R9 counters: VGPR=68 (just over the 64 occupancy cliff: 65-128 VGPR halves
// waves/CU), Occ 21%, hbm 3.1/6.3 TB/s -> latency-bound. Fix: m-outer loop so
// only ONE m-tile's A-frags live (16 VGPR), B re-read from LDS per (m,nt)
// (48 b128/thread, overlappable), acc written out immediately. Live ~55 VGPR;
// __launch_bounds__(256,8) pins the allocator under 64 -> 8 waves/SIMD.
template <int OC>
__global__ __launch_bounds__(256, 8) void k_pwm(const float* in,
                                                const float* __restrict__ w,
                                                float* outp) {
  constexpr int MT = OC / 64;
  __shared__ u16 XTh[64 * PST], XTl[64 * PST];
  const int t = threadIdx.x;
  const int px = t & 63, cg = t >> 6;
  const size_t pix0 = (size_t)blockIdx.x * 64;
  const int b = (int)(pix0 >> 16);
  const int hw0 = (int)(pix0 & 65535);
  const float* ib = in + (((size_t)b * 64) << 16) + hw0 + px;
#pragma unroll
  for (int j = 0; j < 2; ++j) {
    short8 hv, lv;
#pragma unroll
    for (int e = 0; e < 8; ++e) {
      int c = cg * 16 + j * 8 + e;
      float xv = ib[(size_t)c << 16];
      u16 h, l;
      fsplit(xv, h, l);
      hv[e] = (short)h;
      lv[e] = (short)l;
    }
    *(short8*)&XTh[px * PST + cg * 16 + j * 8] = hv;
    *(short8*)&XTl[px * PST + cg * 16 + j * 8] = lv;
  }
  __syncthreads();
  const int wid = t >> 6, g = (t >> 4) & 3, r16 = t & 15;
  const int oc0 = wid * 16 * MT;
  float* ob = outp + (((size_t)b * OC) << 16) + hw0;
#pragma unroll 1
  for (int m = 0; m < MT; ++m) {
    short8 ah[2], al[2];  // only this m's A-frags live
#pragma unroll
    for (int ks = 0; ks < 2; ++ks) {
      const float* wr = w + (oc0 + m * 16 + r16) * 64 + ks * 32 + g * 8;
      float4 a0 = *(const float4*)wr;
      float4 a1 = *(const float4*)(wr + 4);
      float av[8] = {a0.x, a0.y, a0.z, a0.w, a1.x, a1.y, a1.z, a1.w};
      short8 h8, l8;
#pragma unroll
      for (int e = 0; e < 8; ++e) {
        u16 h, l;
        fsplit(av[e], h, l);
        h8[e] = (short)h;
        l8[e] = (short)l;
      }
      ah[ks] = h8;
      al[ks] = l8;
    }
#pragma unroll
    for (int nt = 0; nt < 4; ++nt) {
      short8 bh[2], bl[2];
#pragma unroll
      for (int ks = 0; ks < 2; ++ks) {
        bh[ks] = ldfrag(XTh, nt * 16 + r16, ks * 32 + g * 8);
        bl[ks] = ldfrag(XTl, nt * 16 + r16, ks * 32 + g * 8);
      }
      f4 acc;
#pragma unroll
      for (int e = 0; e < 4; ++e) acc[e] = 0.f;
#pragma unroll
      for (int ks = 0; ks < 2; ++ks) {
        acc = __builtin_amdgcn_mfma_f32_16x16x32_bf16(ah[ks], bh[ks], acc, 0, 0, 0);
        acc = __builtin_amdgcn_mfma_f32_16x16x32_bf16(ah[ks], bl[ks], acc, 0, 0, 0);
        acc = __builtin_amdgcn_mfma_f32_16x16x32_bf16(al[ks], bh[ks], acc, 0, 0, 0);
      }
#pragma unroll
      for (int e = 0; e < 4; ++e) {
        int oc = oc0 + m * 16 + g * 4 + e;
        ob[((size_t)oc << 16) + nt * 16 + r16] = acc[e];
      }
    }
  }
}

// ---- depthwise 3x3 conv: one run = 8 tokens (n=nb..nb+7) at one feature dcol --
__device__ __forceinline__ void conv_run(const float* __restrict__ pl,
                                         const float* __restrict__ w9, int cd,
                                         int r, float o[8], int& nb,
                                         int& dcol) {
  int lr = r >> 5, w0 = r & 31;
  int h = cd * 16 + lr;
  float rv[3][10];
#pragma unroll
  for (int dy = 0; dy < 3; ++dy) {
    int hy = h + dy - 1;
    bool hv = (hy >= 0) && (hy < 256);
#pragma unroll
    for (int j = 0; j < 10; ++j) rv[dy][j] = 0.f;
    if (hv) {
      const float* rp = pl + hy * 256;
      const float4* rp4 = (const float4*)(rp + w0 * 8);
      float4 a = rp4[0], b4 = rp4[1];
      rv[dy][1] = a.x;  rv[dy][2] = a.y;  rv[dy][3] = a.z;  rv[dy][4] = a.w;
      rv[dy][5] = b4.x; rv[dy][6] = b4.y; rv[dy][7] = b4.z; rv[dy][8] = b4.w;
      rv[dy][0] = (w0 > 0) ? rp[w0 * 8 - 1] : 0.f;
      rv[dy][9] = (w0 < 31) ? rp[w0 * 8 + 8] : 0.f;
    }
  }
  nb = (lr & 7) * 8;
  dcol = ((lr >> 3) << 5) + w0;
#pragma unroll
  for (int i = 0; i < 8; ++i) {
    o[i] = fmaf(w9[0], rv[0][i], fmaf(w9[1], rv[0][i + 1], fmaf(w9[2], rv[0][i + 2],
            fmaf(w9[3], rv[1][i], fmaf(w9[4], rv[1][i + 1], fmaf(w9[5], rv[1][i + 2],
            fmaf(w9[6], rv[2][i], fmaf(w9[7], rv[2][i + 1], w9[8] * rv[2][i + 2]))))))));
  }
}

// stage Q/K chunk as hi/lo planes [64 n][PST d]
__device__ __forceinline__ void stage_nk(const float* __restrict__ pl,
                                         const float* __restrict__ w9,
                                         u16* __restrict__ ph,
                                         u16* __restrict__ plo, int cd, int t) {
#pragma unroll
  for (int rr = 0; rr < 2; ++rr) {
    float o[8]; int nb, dcol;
    conv_run(pl, w9, cd, t + rr * 256, o, nb, dcol);
#pragma unroll
    for (int i = 0; i < 8; ++i) {
      u16 h, l;
      fsplit(o[i], h, l);
      ph[(nb + i) * PST + dcol] = h;
      plo[(nb + i) * PST + dcol] = l;
    }
  }
}

// stage V chunk TRANSPOSED [64 d][PST n]: packed b128 writes
__device__ __forceinline__ void stage_vt(const float* __restrict__ pl,
                                         const float* __restrict__ w9,
                                         u16* __restrict__ ph,
                                         u16* __restrict__ plo, int cd, int t) {
#pragma unroll
  for (int rr = 0; rr < 2; ++rr) {
    float o[8]; int nb, dcol;
    conv_run(pl, w9, cd, t + rr * 256, o, nb, dcol);
    short8 hv, lv;
#pragma unroll
    for (int i = 0; i < 8; ++i) {
      u16 h, l;
      fsplit(o[i], h, l);
      hv[i] = (short)h;
      lv[i] = (short)l;
    }
    *(short8*)&ph[dcol * PST + nb] = hv;
    *(short8*)&plo[dcol * PST + nb] = lv;
  }
}

// ---------------- K2a: QK^T partial over a d-half (unchanged R9) ----------------
__global__ __launch_bounds__(256) void k_qkt(float* qkv0,
                                             const float* __restrict__ wdw) {
  __shared__ u16 SAh[64 * PST], SAl[64 * PST];
  __shared__ u16 SBh[64 * PST], SBl[64 * PST];
  __shared__ float red[64 * 8];
  const int t = threadIdx.x;
  const int u = blockIdx.x >> 1, hd = blockIdx.x & 1;
  const int b = u >> 6, ch = u & 63;
  float* qpl = qkv0 + (((size_t)b * 192 + ch) << 16);
  const float* kpl = qkv0 + (((size_t)b * 192 + 64 + ch) << 16);
  float wq[9], wk[9];
#pragma unroll
  for (int i = 0; i < 9; ++i) {
    wq[i] = wdw[ch * 9 + i];
    wk[i] = wdw[(64 + ch) * 9 + i];
  }
  const int wid = t >> 6, g = (t >> 4) & 3, r16 = t & 15;
  f4 acc[4];
#pragma unroll
  for (int cb = 0; cb < 4; ++cb)
#pragma unroll
    for (int e = 0; e < 4; ++e) acc[cb][e] = 0.f;
  float sqQ = 0.f, sqK = 0.f;

  for (int c8 = 0; c8 < 8; ++c8) {
    const int cd = hd * 8 + c8;
    stage_nk(qpl, wq, SAh, SAl, cd, t);
    stage_nk(kpl, wk, SBh, SBl, cd, t);
    __syncthreads();
    {  // sumsq partials (hi+lo reconstructed): row n=t>>2, 16 cols
      const int n = t >> 2, c0 = (t & 3) << 4;
#pragma unroll
      for (int h2 = 0; h2 < 2; ++h2) {
        short8 qh = *(const short8*)&SAh[n * PST + c0 + 8 * h2];
        short8 ql = *(const short8*)&SAl[n * PST + c0 + 8 * h2];
        short8 kh = *(const short8*)&SBh[n * PST + c0 + 8 * h2];
        short8 kl = *(const short8*)&SBl[n * PST + c0 + 8 * h2];
#pragma unroll
        for (int e = 0; e < 8; ++e) {
          float qv = tof((u16)qh[e]) + tof((u16)ql[e]);
          float kv = tof((u16)kh[e]) + tof((u16)kl[e]);
          sqQ = fmaf(qv, qv, sqQ);
          sqK = fmaf(kv, kv, sqK);
        }
      }
    }
#pragma unroll
    for (int ks = 0; ks < 2; ++ks) {
      const int ko = ks * 32 + g * 8;
      short8 ah = ldfrag(SAh, wid * 16 + r16, ko);
      short8 al = ldfrag(SAl, wid * 16 + r16, ko);
#pragma unroll
      for (int cb = 0; cb < 4; ++cb) {
        short8 bh = ldfrag(SBh, cb * 16 + r16, ko);
        short8 bl = ldfrag(SBl, cb * 16 + r16, ko);
        acc[cb] = __builtin_amdgcn_mfma_f32_16x16x32_bf16(ah, bh, acc[cb], 0, 0, 0);
        acc[cb] = __builtin_amdgcn_mfma_f32_16x16x32_bf16(ah, bl, acc[cb], 0, 0, 0);
        acc[cb] = __builtin_amdgcn_mfma_f32_16x16x32_bf16(al, bh, acc[cb], 0, 0, 0);
      }
    }
    __syncthreads();
  }

  red[(t >> 2) * 8 + (t & 3)] = sqQ;
  red[(t >> 2) * 8 + 4 + (t & 3)] = sqK;
  __syncthreads();
  float* stash = qpl + hd * 32768 + 256;  // S[4096] then sumsq[128]
  if (t < 128) {
    int n = t & 63;
    int o = (t >> 6) * 4;
    float s = red[n * 8 + o] + red[n * 8 + o + 1] + red[n * 8 + o + 2] +
              red[n * 8 + o + 3];
    stash[4096 + (t >> 6) * 64 + n] = s;  // 0..63 = Q, 64..127 = K
  }
#pragma unroll
  for (int cb = 0; cb < 4; ++cb)
#pragma unroll
    for (int r = 0; r < 4; ++r) {
      int n = wid * 16 + g * 4 + r, m = cb * 16 + r16;
      stash[n * 64 + m] = acc[cb][r];
    }
}

// ---------------- K2b: softmax + PV over a d-half (unchanged R9) ----------------
__global__ __launch_bounds__(256) void k_pv(const float* qkv0,
                                            const float* __restrict__ wdw,
                                            const float* __restrict__ temperature,
                                            float* __restrict__ out) {
  __shared__ u16 Ph[64 * PST], Pl[64 * PST];
  __shared__ u16 Vh[64 * PST], Vl[64 * PST];
  __shared__ float invk[64];
  const int t = threadIdx.x;
  const int u = blockIdx.x >> 1, hd = blockIdx.x & 1;
  const int b = u >> 6, ch = u & 63;
  const float* vpl = qkv0 + (((size_t)b * 192 + 128 + ch) << 16);
  const float* sb0 = qkv0 + (((size_t)b * 192 + ch) << 16) + 256;
  const float* sb1 = sb0 + 32768;
  float wv[9];
#pragma unroll
  for (int i = 0; i < 9; ++i) wv[i] = wdw[(128 + ch) * 9 + i];
  const float tscale = temperature[ch >> 3];
  const int wid = t >> 6, g = (t >> 4) & 3, r16 = t & 15;

  if (t < 64) {
    float s = sb0[4096 + 64 + t] + sb1[4096 + 64 + t];
    invk[t] = 1.f / fmaxf(sqrtf(s), 1e-12f);
  }
  __syncthreads();

  const int row = wid * 16 + r16;
  float sq = sb0[4096 + row] + sb1[4096 + row];
  const float invq = 1.f / fmaxf(sqrtf(sq), 1e-12f);
  float sv[16];
  const float* s0r = sb0 + row * 64 + g * 16;
  const float* s1r = sb1 + row * 64 + g * 16;
  float mx = -1e30f;
#pragma unroll
  for (int j = 0; j < 16; ++j) {
    sv[j] = (s0r[j] + s1r[j]) * invq * invk[g * 16 + j] * tscale;
    mx = fmaxf(mx, sv[j]);
  }
  mx = fmaxf(mx, __shfl_xor(mx, 16));
  mx = fmaxf(mx, __shfl_xor(mx, 32));
  float ss = 0.f;
#pragma unroll
  for (int j = 0; j < 16; ++j) {
    sv[j] = __expf(sv[j] - mx);
    ss += sv[j];
  }
  ss += __shfl_xor(ss, 16);
  ss += __shfl_xor(ss, 32);
  const float rs = 1.f / ss;
  short8 h0, h1, l0, l1;
#pragma unroll
  for (int j = 0; j < 8; ++j) {
    u16 h, l;
    fsplit(sv[j] * rs, h, l);
    h0[j] = (short)h; l0[j] = (short)l;
    fsplit(sv[8 + j] * rs, h, l);
    h1[j] = (short)h; l1[j] = (short)l;
  }
  *(short8*)&Ph[row * PST + g * 16] = h0;
  *(short8*)&Ph[row * PST + g * 16 + 8] = h1;
  *(short8*)&Pl[row * PST + g * 16] = l0;
  *(short8*)&Pl[row * PST + g * 16 + 8] = l1;
  __syncthreads();

  short8 pah[2], pal[2];
#pragma unroll
  for (int ks = 0; ks < 2; ++ks) {
    pah[ks] = ldfrag(Ph, wid * 16 + r16, ks * 32 + g * 8);
    pal[ks] = ldfrag(Pl, wid * 16 + r16, ks * 32 + g * 8);
  }

  size_t obase = ((size_t)b * 64 + ch) << 16;
  for (int c8 = 0; c8 < 8; ++c8) {
    const int cd = hd * 8 + c8;
    stage_vt(vpl, wv, Vh, Vl, cd, t);
    __syncthreads();
    f4 po[4];
#pragma unroll
    for (int cb = 0; cb < 4; ++cb)
#pragma unroll
      for (int e = 0; e < 4; ++e) po[cb][e] = 0.f;
#pragma unroll
    for (int ks = 0; ks < 2; ++ks) {
      const int ko = ks * 32 + g * 8;
#pragma unroll
      for (int cb = 0; cb < 4; ++cb) {
        short8 bh = ldfrag(Vh, cb * 16 + r16, ko);
        short8 bl = ldfrag(Vl, cb * 16 + r16, ko);
        po[cb] = __builtin_amdgcn_mfma_f32_16x16x32_bf16(pah[ks], bh, po[cb], 0, 0, 0);
        po[cb] = __builtin_amdgcn_mfma_f32_16x16x32_bf16(pah[ks], bl, po[cb], 0, 0, 0);
        po[cb] = __builtin_amdgcn_mfma_f32_16x16x32_bf16(pal[ks], bh, po[cb], 0, 0, 0);
      }
    }
#pragma unroll
    for (int cb = 0; cb < 4; ++cb)
#pragma unroll
      for (int r = 0; r < 4; ++r) {
        int n = wid * 16 + g * 4 + r;
        int d = cd * 64 + cb * 16 + r16;
        int hh = ((d >> 5) << 3) + (n >> 3);
        int ww = ((d & 31) << 3) + (n & 7);
        out[obase + hh * 256 + ww] = po[cb][r];
      }
    __syncthreads();
  }
}

extern "C" void kernel_launch(void* const* d_in, const int* in_sizes, int n_in,
                              void* d_out, int out_size, void* d_ws,
                              size_t ws_size, hipStream_t stream) {
  const float* x = (const float*)d_in[0];
  const float* wqkv = (const float*)d_in[1];
  const float* wdw = (const float*)d_in[2];
  const float* wproj = (const float*)d_in[3];
  const float* temp = (const float*)d_in[4];
  float* out = (float*)d_out;
  float* qkv0 = (float*)d_ws;  // 402,653,184 bytes (S/sumsq stash inside)

  k_pwm<192><<<8192, 256, 0, stream>>>(x, wqkv, qkv0);
  k_qkt<<<1024, 256, 0, stream>>>(qkv0, wdw);
  k_pv<<<1024, 256, 0, stream>>>(qkv0, wdw, temp, out);
  k_pwm<64><<<8192, 256, 0, stream>>>(out, wproj, out);
}

// Round 11
// 399.256 us; speedup vs baseline: 1.6087x; 1.6087x over previous
//
#include <hip/hip_runtime.h>
#include <hip/hip_bf16.h>

// CxNNxNN attention. B=8, C=64, H=W=256, head=8, N=8.
// token n = (h&7)*8 + (w&7)  [64], feature d = (h>>3)*32 + (w>>3)  [1024].

typedef __attribute__((ext_vector_type(8))) short short8;  // 8 bf16 (4 VGPR)
typedef __attribute__((ext_vector_type(4))) float f4;      // MFMA acc
typedef unsigned short u16;

#define PST 72  // bf16 plane row stride (ushorts)

// ---------------- bf16 hi/lo helpers ----------------
__device__ __forceinline__ float tof(u16 u) {
  return __builtin_bit_cast(float, ((unsigned)u) << 16);
}
__device__ __forceinline__ void fsplit(float o, u16& h, u16& l) {
  unsigned u = __builtin_bit_cast(unsigned, o);
  h = (u16)(u >> 16);  // truncate; lo compensates
  float hf = __builtin_bit_cast(float, o == o ? (__builtin_bit_cast(unsigned, o) & 0xffff0000u) : 0u);
  l = (u16)(__builtin_bit_cast(unsigned, o - hf) >> 16);
}
__device__ __forceinline__ short8 ldfrag(const u16* p, int row, int ko) {
  return *(const short8*)&p[row * PST + ko];
}

// ---------------- K1/K3: pointwise GEMM on MFMA ----------------
// R9: all-m-live -> VGPR=68 (just over 64 cliff), 151us. R10: forced
// launch_bounds(256,8) -> allocator spilled (VGPR=32, +800MB scratch
// traffic, 404us). R11: NO forced bound; live set shrunk by construction:
// m-outer (one m-tile's A-frags live = 16 VGPR) + per-ks B-loads (8) +
// single f4 acc (4). Natural alloc should land <=64 -> 8 waves/SIMD;
// worst case ~68 -> R9 perf, no spill possible.
template <int OC>
__global__ __launch_bounds__(256) void k_pwm(const float* in,
                                             const float* __restrict__ w,
                                             float* outp) {
  constexpr int MT = OC / 64;
  __shared__ u16 XTh[64 * PST], XTl[64 * PST];
  const int t = threadIdx.x;
  const int px = t & 63, cg = t >> 6;
  const size_t pix0 = (size_t)blockIdx.x * 64;
  const int b = (int)(pix0 >> 16);
  const int hw0 = (int)(pix0 & 65535);
  const float* ib = in + (((size_t)b * 64) << 16) + hw0 + px;
#pragma unroll
  for (int j = 0; j < 2; ++j) {
    short8 hv, lv;
#pragma unroll
    for (int e = 0; e < 8; ++e) {
      int c = cg * 16 + j * 8 + e;
      float xv = ib[(size_t)c << 16];
      unsigned uu = __builtin_bit_cast(unsigned, xv);
      u16 h = (u16)(uu >> 16);
      float hf = __builtin_bit_cast(float, uu & 0xffff0000u);
      u16 l = (u16)(__builtin_bit_cast(unsigned, xv - hf) >> 16);
      hv[e] = (short)h;
      lv[e] = (short)l;
    }
    *(short8*)&XTh[px * PST + cg * 16 + j * 8] = hv;
    *(short8*)&XTl[px * PST + cg * 16 + j * 8] = lv;
  }
  __syncthreads();
  const int wid = t >> 6, g = (t >> 4) & 3, r16 = t & 15;
  const int oc0 = wid * 16 * MT;
  float* ob = outp + (((size_t)b * OC) << 16) + hw0;
#pragma unroll 1
  for (int m = 0; m < MT; ++m) {
    short8 ah[2], al[2];  // only this m's A-frags live (16 VGPR)
#pragma unroll
    for (int ks = 0; ks < 2; ++ks) {
      const float* wr = w + (oc0 + m * 16 + r16) * 64 + ks * 32 + g * 8;
      float4 a0 = *(const float4*)wr;
      float4 a1 = *(const float4*)(wr + 4);
      float av[8] = {a0.x, a0.y, a0.z, a0.w, a1.x, a1.y, a1.z, a1.w};
      short8 h8, l8;
#pragma unroll
      for (int e = 0; e < 8; ++e) {
        unsigned uu = __builtin_bit_cast(unsigned, av[e]);
        u16 h = (u16)(uu >> 16);
        float hf = __builtin_bit_cast(float, uu & 0xffff0000u);
        u16 l = (u16)(__builtin_bit_cast(unsigned, av[e] - hf) >> 16);
        h8[e] = (short)h;
        l8[e] = (short)l;
      }
      ah[ks] = h8;
      al[ks] = l8;
    }
#pragma unroll
    for (int nt = 0; nt < 4; ++nt) {
      f4 acc;
#pragma unroll
      for (int e = 0; e < 4; ++e) acc[e] = 0.f;
#pragma unroll
      for (int ks = 0; ks < 2; ++ks) {  // one ks's B-frags live (8 VGPR)
        short8 bh = ldfrag(XTh, nt * 16 + r16, ks * 32 + g * 8);
        short8 bl = ldfrag(XTl, nt * 16 + r16, ks * 32 + g * 8);
        acc = __builtin_amdgcn_mfma_f32_16x16x32_bf16(ah[ks], bh, acc, 0, 0, 0);
        acc = __builtin_amdgcn_mfma_f32_16x16x32_bf16(ah[ks], bl, acc, 0, 0, 0);
        acc = __builtin_amdgcn_mfma_f32_16x16x32_bf16(al[ks], bh, acc, 0, 0, 0);
      }
#pragma unroll
      for (int e = 0; e < 4; ++e) {
        int oc = oc0 + m * 16 + g * 4 + e;
        ob[((size_t)oc << 16) + nt * 16 + r16] = acc[e];
      }
    }
  }
}

// ---- depthwise 3x3 conv: one run = 8 tokens (n=nb..nb+7) at one feature dcol --
__device__ __forceinline__ void conv_run(const float* __restrict__ pl,
                                         const float* __restrict__ w9, int cd,
                                         int r, float o[8], int& nb,
                                         int& dcol) {
  int lr = r >> 5, w0 = r & 31;
  int h = cd * 16 + lr;
  float rv[3][10];
#pragma unroll
  for (int dy = 0; dy < 3; ++dy) {
    int hy = h + dy - 1;
    bool hv = (hy >= 0) && (hy < 256);
#pragma unroll
    for (int j = 0; j < 10; ++j) rv[dy][j] = 0.f;
    if (hv) {
      const float* rp = pl + hy * 256;
      const float4* rp4 = (const float4*)(rp + w0 * 8);
      float4 a = rp4[0], b4 = rp4[1];
      rv[dy][1] = a.x;  rv[dy][2] = a.y;  rv[dy][3] = a.z;  rv[dy][4] = a.w;
      rv[dy][5] = b4.x; rv[dy][6] = b4.y; rv[dy][7] = b4.z; rv[dy][8] = b4.w;
      rv[dy][0] = (w0 > 0) ? rp[w0 * 8 - 1] : 0.f;
      rv[dy][9] = (w0 < 31) ? rp[w0 * 8 + 8] : 0.f;
    }
  }
  nb = (lr & 7) * 8;
  dcol = ((lr >> 3) << 5) + w0;
#pragma unroll
  for (int i = 0; i < 8; ++i) {
    o[i] = fmaf(w9[0], rv[0][i], fmaf(w9[1], rv[0][i + 1], fmaf(w9[2], rv[0][i + 2],
            fmaf(w9[3], rv[1][i], fmaf(w9[4], rv[1][i + 1], fmaf(w9[5], rv[1][i + 2],
            fmaf(w9[6], rv[2][i], fmaf(w9[7], rv[2][i + 1], w9[8] * rv[2][i + 2]))))))));
  }
}

// stage Q/K chunk as hi/lo planes [64 n][PST d]
__device__ __forceinline__ void stage_nk(const float* __restrict__ pl,
                                         const float* __restrict__ w9,
                                         u16* __restrict__ ph,
                                         u16* __restrict__ plo, int cd, int t) {
#pragma unroll
  for (int rr = 0; rr < 2; ++rr) {
    float o[8]; int nb, dcol;
    conv_run(pl, w9, cd, t + rr * 256, o, nb, dcol);
#pragma unroll
    for (int i = 0; i < 8; ++i) {
      u16 h, l;
      fsplit(o[i], h, l);
      ph[(nb + i) * PST + dcol] = h;
      plo[(nb + i) * PST + dcol] = l;
    }
  }
}

// stage V chunk TRANSPOSED [64 d][PST n]: packed b128 writes
__device__ __forceinline__ void stage_vt(const float* __restrict__ pl,
                                         const float* __restrict__ w9,
                                         u16* __restrict__ ph,
                                         u16* __restrict__ plo, int cd, int t) {
#pragma unroll
  for (int rr = 0; rr < 2; ++rr) {
    float o[8]; int nb, dcol;
    conv_run(pl, w9, cd, t + rr * 256, o, nb, dcol);
    short8 hv, lv;
#pragma unroll
    for (int i = 0; i < 8; ++i) {
      u16 h, l;
      fsplit(o[i], h, l);
      hv[i] = (short)h;
      lv[i] = (short)l;
    }
    *(short8*)&ph[dcol * PST + nb] = hv;
    *(short8*)&plo[dcol * PST + nb] = lv;
  }
}

// ---------------- K2a: QK^T partial over a d-half (unchanged R9) ----------------
__global__ __launch_bounds__(256) void k_qkt(float* qkv0,
                                             const float* __restrict__ wdw) {
  __shared__ u16 SAh[64 * PST], SAl[64 * PST];
  __shared__ u16 SBh[64 * PST], SBl[64 * PST];
  __shared__ float red[64 * 8];
  const int t = threadIdx.x;
  const int u = blockIdx.x >> 1, hd = blockIdx.x & 1;
  const int b = u >> 6, ch = u & 63;
  float* qpl = qkv0 + (((size_t)b * 192 + ch) << 16);
  const float* kpl = qkv0 + (((size_t)b * 192 + 64 + ch) << 16);
  float wq[9], wk[9];
#pragma unroll
  for (int i = 0; i < 9; ++i) {
    wq[i] = wdw[ch * 9 + i];
    wk[i] = wdw[(64 + ch) * 9 + i];
  }
  const int wid = t >> 6, g = (t >> 4) & 3, r16 = t & 15;
  f4 acc[4];
#pragma unroll
  for (int cb = 0; cb < 4; ++cb)
#pragma unroll
    for (int e = 0; e < 4; ++e) acc[cb][e] = 0.f;
  float sqQ = 0.f, sqK = 0.f;

  for (int c8 = 0; c8 < 8; ++c8) {
    const int cd = hd * 8 + c8;
    stage_nk(qpl, wq, SAh, SAl, cd, t);
    stage_nk(kpl, wk, SBh, SBl, cd, t);
    __syncthreads();
    {  // sumsq partials (hi+lo reconstructed): row n=t>>2, 16 cols
      const int n = t >> 2, c0 = (t & 3) << 4;
#pragma unroll
      for (int h2 = 0; h2 < 2; ++h2) {
        short8 qh = *(const short8*)&SAh[n * PST + c0 + 8 * h2];
        short8 ql = *(const short8*)&SAl[n * PST + c0 + 8 * h2];
        short8 kh = *(const short8*)&SBh[n * PST + c0 + 8 * h2];
        short8 kl = *(const short8*)&SBl[n * PST + c0 + 8 * h2];
#pragma unroll
        for (int e = 0; e < 8; ++e) {
          float qv = tof((u16)qh[e]) + tof((u16)ql[e]);
          float kv = tof((u16)kh[e]) + tof((u16)kl[e]);
          sqQ = fmaf(qv, qv, sqQ);
          sqK = fmaf(kv, kv, sqK);
        }
      }
    }
#pragma unroll
    for (int ks = 0; ks < 2; ++ks) {
      const int ko = ks * 32 + g * 8;
      short8 ah = ldfrag(SAh, wid * 16 + r16, ko);
      short8 al = ldfrag(SAl, wid * 16 + r16, ko);
#pragma unroll
      for (int cb = 0; cb < 4; ++cb) {
        short8 bh = ldfrag(SBh, cb * 16 + r16, ko);
        short8 bl = ldfrag(SBl, cb * 16 + r16, ko);
        acc[cb] = __builtin_amdgcn_mfma_f32_16x16x32_bf16(ah, bh, acc[cb], 0, 0, 0);
        acc[cb] = __builtin_amdgcn_mfma_f32_16x16x32_bf16(ah, bl, acc[cb], 0, 0, 0);
        acc[cb] = __builtin_amdgcn_mfma_f32_16x16x32_bf16(al, bh, acc[cb], 0, 0, 0);
      }
    }
    __syncthreads();
  }

  red[(t >> 2) * 8 + (t & 3)] = sqQ;
  red[(t >> 2) * 8 + 4 + (t & 3)] = sqK;
  __syncthreads();
  float* stash = qpl + hd * 32768 + 256;  // S[4096] then sumsq[128]
  if (t < 128) {
    int n = t & 63;
    int o = (t >> 6) * 4;
    float s = red[n * 8 + o] + red[n * 8 + o + 1] + red[n * 8 + o + 2] +
              red[n * 8 + o + 3];
    stash[4096 + (t >> 6) * 64 + n] = s;  // 0..63 = Q, 64..127 = K
  }
#pragma unroll
  for (int cb = 0; cb < 4; ++cb)
#pragma unroll
    for (int r = 0; r < 4; ++r) {
      int n = wid * 16 + g * 4 + r, m = cb * 16 + r16;
      stash[n * 64 + m] = acc[cb][r];
    }
}

// ---------------- K2b: softmax + PV over a d-half (unchanged R9) ----------------
__global__ __launch_bounds__(256) void k_pv(const float* qkv0,
                                            const float* __restrict__ wdw,
                                            const float* __restrict__ temperature,
                                            float* __restrict__ out) {
  __shared__ u16 Ph[64 * PST], Pl[64 * PST];
  __shared__ u16 Vh[64 * PST], Vl[64 * PST];
  __shared__ float invk[64];
  const int t = threadIdx.x;
  const int u = blockIdx.x >> 1, hd = blockIdx.x & 1;
  const int b = u >> 6, ch = u & 63;
  const float* vpl = qkv0 + (((size_t)b * 192 + 128 + ch) << 16);
  const float* sb0 = qkv0 + (((size_t)b * 192 + ch) << 16) + 256;
  const float* sb1 = sb0 + 32768;
  float wv[9];
#pragma unroll
  for (int i = 0; i < 9; ++i) wv[i] = wdw[(128 + ch) * 9 + i];
  const float tscale = temperature[ch >> 3];
  const int wid = t >> 6, g = (t >> 4) & 3, r16 = t & 15;

  if (t < 64) {
    float s = sb0[4096 + 64 + t] + sb1[4096 + 64 + t];
    invk[t] = 1.f / fmaxf(sqrtf(s), 1e-12f);
  }
  __syncthreads();

  const int row = wid * 16 + r16;
  float sq = sb0[4096 + row] + sb1[4096 + row];
  const float invq = 1.f / fmaxf(sqrtf(sq), 1e-12f);
  float sv[16];
  const float* s0r = sb0 + row * 64 + g * 16;
  const float* s1r = sb1 + row * 64 + g * 16;
  float mx = -1e30f;
#pragma unroll
  for (int j = 0; j < 16; ++j) {
    sv[j] = (s0r[j] + s1r[j]) * invq * invk[g * 16 + j] * tscale;
    mx = fmaxf(mx, sv[j]);
  }
  mx = fmaxf(mx, __shfl_xor(mx, 16));
  mx = fmaxf(mx, __shfl_xor(mx, 32));
  float ss = 0.f;
#pragma unroll
  for (int j = 0; j < 16; ++j) {
    sv[j] = __expf(sv[j] - mx);
    ss += sv[j];
  }
  ss += __shfl_xor(ss, 16);
  ss += __shfl_xor(ss, 32);
  const float rs = 1.f / ss;
  short8 h0, h1, l0, l1;
#pragma unroll
  for (int j = 0; j < 8; ++j) {
    u16 h, l;
    fsplit(sv[j] * rs, h, l);
    h0[j] = (short)h; l0[j] = (short)l;
    fsplit(sv[8 + j] * rs, h, l);
    h1[j] = (short)h; l1[j] = (short)l;
  }
  *(short8*)&Ph[row * PST + g * 16] = h0;
  *(short8*)&Ph[row * PST + g * 16 + 8] = h1;
  *(short8*)&Pl[row * PST + g * 16] = l0;
  *(short8*)&Pl[row * PST + g * 16 + 8] = l1;
  __syncthreads();

  short8 pah[2], pal[2];
#pragma unroll
  for (int ks = 0; ks < 2; ++ks) {
    pah[ks] = ldfrag(Ph, wid * 16 + r16, ks * 32 + g * 8);
    pal[ks] = ldfrag(Pl, wid * 16 + r16, ks * 32 + g * 8);
  }

  size_t obase = ((size_t)b * 64 + ch) << 16;
  for (int c8 = 0; c8 < 8; ++c8) {
    const int cd = hd * 8 + c8;
    stage_vt(vpl, wv, Vh, Vl, cd, t);
    __syncthreads();
    f4 po[4];
#pragma unroll
    for (int cb = 0; cb < 4; ++cb)
#pragma unroll
      for (int e = 0; e < 4; ++e) po[cb][e] = 0.f;
#pragma unroll
    for (int ks = 0; ks < 2; ++ks) {
      const int ko = ks * 32 + g * 8;
#pragma unroll
      for (int cb = 0; cb < 4; ++cb) {
        short8 bh = ldfrag(Vh, cb * 16 + r16, ko);
        short8 bl = ldfrag(Vl, cb * 16 + r16, ko);
        po[cb] = __builtin_amdgcn_mfma_f32_16x16x32_bf16(pah[ks], bh, po[cb], 0, 0, 0);
        po[cb] = __builtin_amdgcn_mfma_f32_16x16x32_bf16(pah[ks], bl, po[cb], 0, 0, 0);
        po[cb] = __builtin_amdgcn_mfma_f32_16x16x32_bf16(pal[ks], bh, po[cb], 0, 0, 0);
      }
    }
#pragma unroll
    for (int cb = 0; cb < 4; ++cb)
#pragma unroll
      for (int r = 0; r < 4; ++r) {
        int n = wid * 16 + g * 4 + r;
        int d = cd * 64 + cb * 16 + r16;
        int hh = ((d >> 5) << 3) + (n >> 3);
        int ww = ((d & 31) << 3) + (n & 7);
        out[obase + hh * 256 + ww] = po[cb][r];
      }
    __syncthreads();
  }
}

extern "C" void kernel_launch(void* const* d_in, const int* in_sizes, int n_in,
                              void* d_out, int out_size, void* d_ws,
                              size_t ws_size, hipStream_t stream) {
  const float* x = (const float*)d_in[0];
  const float* wqkv = (const float*)d_in[1];
  const float* wdw = (const float*)d_in[2];
  const float* wproj = (const float*)d_in[3];
  const float* temp = (const float*)d_in[4];
  float* out = (float*)d_out;
  float* qkv0 = (float*)d_ws;  // 402,653,184 bytes (S/sumsq stash inside)

  k_pwm<192><<<8192, 256, 0, stream>>>(x, wqkv, qkv0);
  k_qkt<<<1024, 256, 0, stream>>>(qkv0, wdw);
  k_pv<<<1024, 256, 0, stream>>>(qkv0, wdw, temp, out);
  k_pwm<64><<<8192, 256, 0, stream>>>(out, wproj, out);
}

// Round 12
// 356.169 us; speedup vs baseline: 1.8033x; 1.1210x over previous
//
#include <hip/hip_runtime.h>
#include <hip/hip_bf16.h>

// CxNNxNN attention. B=8, C=64, H=W=256, head=8, N=8.
// token n = (h&7)*8 + (w&7)  [64], feature d = (h>>3)*32 + (w>>3)  [1024].

typedef __attribute__((ext_vector_type(8))) short short8;  // 8 bf16 (4 VGPR)
typedef __attribute__((ext_vector_type(4))) float f4;      // MFMA acc
typedef unsigned short u16;

#define PST 72  // bf16 plane row stride (ushorts)

// ---------------- bf16 hi/lo helpers ----------------
__device__ __forceinline__ float tof(u16 u) {
  return __builtin_bit_cast(float, ((unsigned)u) << 16);
}
__device__ __forceinline__ void fsplit(float o, u16& h, u16& l) {
  unsigned u = __builtin_bit_cast(unsigned, o);
  h = (u16)(u >> 16);  // truncate; lo compensates
  float hf = __builtin_bit_cast(float, u & 0xffff0000u);
  l = (u16)(__builtin_bit_cast(unsigned, o - hf) >> 16);
}
__device__ __forceinline__ short8 ldfrag(const u16* p, int row, int ko) {
  return *(const short8*)&p[row * PST + ko];
}

// ---------------- K1/K3: pointwise GEMM on MFMA ----------------
// R11: VGPR=52, traffic ideal, but 147us @ hbm 3.2TB/s, VALU 16% -- latency
// bound with ZERO memory/compute overlap inside a block (stage, barrier,
// compute, done). R12: persistent 4-tile blocks (grid 2048): weights
// loaded+split ONCE; per tile, next tile's 16 x-loads are issued right
// after the staging barrier so they fly under the MFMA+store phase (T14
// issue-early/consume-late). Next ds_write's reg dependency = vmcnt wait.
template <int OC>
__global__ __launch_bounds__(256) void k_pwm(const float* in,
                                             const float* __restrict__ w,
                                             float* outp) {
  constexpr int MT = OC / 64;
  __shared__ u16 XTh[64 * PST], XTl[64 * PST];
  const int t = threadIdx.x;
  const int px = t & 63, cg = t >> 6;
  const int g = (t >> 4) & 3, r16 = t & 15;
  const int oc0 = cg * 16 * MT;
  const size_t pix0 = (size_t)blockIdx.x * 256;  // 4 tiles of 64 px
  const int b = (int)(pix0 >> 16);
  const int hwb = (int)(pix0 & 65535);
  const float* ibase = in + ((size_t)b << 22);

  // A-frags (weights) once per block, hi/lo split in-register
  short8 ah[MT][2], al[MT][2];
#pragma unroll
  for (int m = 0; m < MT; ++m)
#pragma unroll
    for (int ks = 0; ks < 2; ++ks) {
      const float* wr = w + (oc0 + m * 16 + r16) * 64 + ks * 32 + g * 8;
      float4 a0 = *(const float4*)wr;
      float4 a1 = *(const float4*)(wr + 4);
      float av[8] = {a0.x, a0.y, a0.z, a0.w, a1.x, a1.y, a1.z, a1.w};
      short8 h8, l8;
#pragma unroll
      for (int e = 0; e < 8; ++e) {
        u16 h, l;
        fsplit(av[e], h, l);
        h8[e] = (short)h;
        l8[e] = (short)l;
      }
      ah[m][ks] = h8;
      al[m][ks] = l8;
    }

  // prefetch tile 0's x (16 c-strided dwords, coalesced 256B/wave)
  float xr[16];
#pragma unroll
  for (int j = 0; j < 16; ++j)
    xr[j] = ibase[((size_t)(cg * 16 + j) << 16) + hwb + px];

#pragma unroll 1
  for (int tau = 0; tau < 4; ++tau) {
    const int hw0 = hwb + tau * 64;
    // split + stage current tile from regs
#pragma unroll
    for (int jh = 0; jh < 2; ++jh) {
      short8 hv, lv;
#pragma unroll
      for (int e = 0; e < 8; ++e) {
        u16 h, l;
        fsplit(xr[jh * 8 + e], h, l);
        hv[e] = (short)h;
        lv[e] = (short)l;
      }
      *(short8*)&XTh[px * PST + cg * 16 + jh * 8] = hv;
      *(short8*)&XTl[px * PST + cg * 16 + jh * 8] = lv;
    }
    __syncthreads();
    if (tau < 3) {  // issue next tile's loads; they fly under compute
#pragma unroll
      for (int j = 0; j < 16; ++j)
        xr[j] = ibase[((size_t)(cg * 16 + j) << 16) + hw0 + 64 + px];
    }
    float* ob = outp + (((size_t)b * OC) << 16) + hw0;
#pragma unroll
    for (int m = 0; m < MT; ++m)
#pragma unroll
      for (int nt = 0; nt < 4; ++nt) {
        f4 acc;
#pragma unroll
        for (int e = 0; e < 4; ++e) acc[e] = 0.f;
#pragma unroll
        for (int ks = 0; ks < 2; ++ks) {
          short8 bh = ldfrag(XTh, nt * 16 + r16, ks * 32 + g * 8);
          short8 bl = ldfrag(XTl, nt * 16 + r16, ks * 32 + g * 8);
          acc = __builtin_amdgcn_mfma_f32_16x16x32_bf16(ah[m][ks], bh, acc, 0, 0, 0);
          acc = __builtin_amdgcn_mfma_f32_16x16x32_bf16(ah[m][ks], bl, acc, 0, 0, 0);
          acc = __builtin_amdgcn_mfma_f32_16x16x32_bf16(al[m][ks], bh, acc, 0, 0, 0);
        }
#pragma unroll
        for (int e = 0; e < 4; ++e) {
          int oc = oc0 + m * 16 + g * 4 + e;
          ob[((size_t)oc << 16) + nt * 16 + r16] = acc[e];
        }
      }
    __syncthreads();  // all ds_reads of this tile done before next ds_write
  }
}

// ---- depthwise 3x3 conv: one run = 8 tokens (n=nb..nb+7) at one feature dcol --
__device__ __forceinline__ void conv_run(const float* __restrict__ pl,
                                         const float* __restrict__ w9, int cd,
                                         int r, float o[8], int& nb,
                                         int& dcol) {
  int lr = r >> 5, w0 = r & 31;
  int h = cd * 16 + lr;
  float rv[3][10];
#pragma unroll
  for (int dy = 0; dy < 3; ++dy) {
    int hy = h + dy - 1;
    bool hv = (hy >= 0) && (hy < 256);
#pragma unroll
    for (int j = 0; j < 10; ++j) rv[dy][j] = 0.f;
    if (hv) {
      const float* rp = pl + hy * 256;
      const float4* rp4 = (const float4*)(rp + w0 * 8);
      float4 a = rp4[0], b4 = rp4[1];
      rv[dy][1] = a.x;  rv[dy][2] = a.y;  rv[dy][3] = a.z;  rv[dy][4] = a.w;
      rv[dy][5] = b4.x; rv[dy][6] = b4.y; rv[dy][7] = b4.z; rv[dy][8] = b4.w;
      rv[dy][0] = (w0 > 0) ? rp[w0 * 8 - 1] : 0.f;
      rv[dy][9] = (w0 < 31) ? rp[w0 * 8 + 8] : 0.f;
    }
  }
  nb = (lr & 7) * 8;
  dcol = ((lr >> 3) << 5) + w0;
#pragma unroll
  for (int i = 0; i < 8; ++i) {
    o[i] = fmaf(w9[0], rv[0][i], fmaf(w9[1], rv[0][i + 1], fmaf(w9[2], rv[0][i + 2],
            fmaf(w9[3], rv[1][i], fmaf(w9[4], rv[1][i + 1], fmaf(w9[5], rv[1][i + 2],
            fmaf(w9[6], rv[2][i], fmaf(w9[7], rv[2][i + 1], w9[8] * rv[2][i + 2]))))))));
  }
}

// stage Q/K chunk as hi/lo planes [64 n][PST d]
__device__ __forceinline__ void stage_nk(const float* __restrict__ pl,
                                         const float* __restrict__ w9,
                                         u16* __restrict__ ph,
                                         u16* __restrict__ plo, int cd, int t) {
#pragma unroll
  for (int rr = 0; rr < 2; ++rr) {
    float o[8]; int nb, dcol;
    conv_run(pl, w9, cd, t + rr * 256, o, nb, dcol);
#pragma unroll
    for (int i = 0; i < 8; ++i) {
      u16 h, l;
      fsplit(o[i], h, l);
      ph[(nb + i) * PST + dcol] = h;
      plo[(nb + i) * PST + dcol] = l;
    }
  }
}

// stage V chunk TRANSPOSED [64 d][PST n]: packed b128 writes
__device__ __forceinline__ void stage_vt(const float* __restrict__ pl,
                                         const float* __restrict__ w9,
                                         u16* __restrict__ ph,
                                         u16* __restrict__ plo, int cd, int t) {
#pragma unroll
  for (int rr = 0; rr < 2; ++rr) {
    float o[8]; int nb, dcol;
    conv_run(pl, w9, cd, t + rr * 256, o, nb, dcol);
    short8 hv, lv;
#pragma unroll
    for (int i = 0; i < 8; ++i) {
      u16 h, l;
      fsplit(o[i], h, l);
      hv[i] = (short)h;
      lv[i] = (short)l;
    }
    *(short8*)&ph[dcol * PST + nb] = hv;
    *(short8*)&plo[dcol * PST + nb] = lv;
  }
}

// ---------------- K2a: QK^T partial over a d-half (unchanged R9) ----------------
__global__ __launch_bounds__(256) void k_qkt(float* qkv0,
                                             const float* __restrict__ wdw) {
  __shared__ u16 SAh[64 * PST], SAl[64 * PST];
  __shared__ u16 SBh[64 * PST], SBl[64 * PST];
  __shared__ float red[64 * 8];
  const int t = threadIdx.x;
  const int u = blockIdx.x >> 1, hd = blockIdx.x & 1;
  const int b = u >> 6, ch = u & 63;
  float* qpl = qkv0 + (((size_t)b * 192 + ch) << 16);
  const float* kpl = qkv0 + (((size_t)b * 192 + 64 + ch) << 16);
  float wq[9], wk[9];
#pragma unroll
  for (int i = 0; i < 9; ++i) {
    wq[i] = wdw[ch * 9 + i];
    wk[i] = wdw[(64 + ch) * 9 + i];
  }
  const int wid = t >> 6, g = (t >> 4) & 3, r16 = t & 15;
  f4 acc[4];
#pragma unroll
  for (int cb = 0; cb < 4; ++cb)
#pragma unroll
    for (int e = 0; e < 4; ++e) acc[cb][e] = 0.f;
  float sqQ = 0.f, sqK = 0.f;

  for (int c8 = 0; c8 < 8; ++c8) {
    const int cd = hd * 8 + c8;
    stage_nk(qpl, wq, SAh, SAl, cd, t);
    stage_nk(kpl, wk, SBh, SBl, cd, t);
    __syncthreads();
    {
      const int n = t >> 2, c0 = (t & 3) << 4;
#pragma unroll
      for (int h2 = 0; h2 < 2; ++h2) {
        short8 qh = *(const short8*)&SAh[n * PST + c0 + 8 * h2];
        short8 ql = *(const short8*)&SAl[n * PST + c0 + 8 * h2];
        short8 kh = *(const short8*)&SBh[n * PST + c0 + 8 * h2];
        short8 kl = *(const short8*)&SBl[n * PST + c0 + 8 * h2];
#pragma unroll
        for (int e = 0; e < 8; ++e) {
          float qv = tof((u16)qh[e]) + tof((u16)ql[e]);
          float kv = tof((u16)kh[e]) + tof((u16)kl[e]);
          sqQ = fmaf(qv, qv, sqQ);
          sqK = fmaf(kv, kv, sqK);
        }
      }
    }
#pragma unroll
    for (int ks = 0; ks < 2; ++ks) {
      const int ko = ks * 32 + g * 8;
      short8 ah = ldfrag(SAh, wid * 16 + r16, ko);
      short8 al = ldfrag(SAl, wid * 16 + r16, ko);
#pragma unroll
      for (int cb = 0; cb < 4; ++cb) {
        short8 bh = ldfrag(SBh, cb * 16 + r16, ko);
        short8 bl = ldfrag(SBl, cb * 16 + r16, ko);
        acc[cb] = __builtin_amdgcn_mfma_f32_16x16x32_bf16(ah, bh, acc[cb], 0, 0, 0);
        acc[cb] = __builtin_amdgcn_mfma_f32_16x16x32_bf16(ah, bl, acc[cb], 0, 0, 0);
        acc[cb] = __builtin_amdgcn_mfma_f32_16x16x32_bf16(al, bh, acc[cb], 0, 0, 0);
      }
    }
    __syncthreads();
  }

  red[(t >> 2) * 8 + (t & 3)] = sqQ;
  red[(t >> 2) * 8 + 4 + (t & 3)] = sqK;
  __syncthreads();
  float* stash = qpl + hd * 32768 + 256;  // S[4096] then sumsq[128]
  if (t < 128) {
    int n = t & 63;
    int o = (t >> 6) * 4;
    float s = red[n * 8 + o] + red[n * 8 + o + 1] + red[n * 8 + o + 2] +
              red[n * 8 + o + 3];
    stash[4096 + (t >> 6) * 64 + n] = s;  // 0..63 = Q, 64..127 = K
  }
#pragma unroll
  for (int cb = 0; cb < 4; ++cb)
#pragma unroll
    for (int r = 0; r < 4; ++r) {
      int n = wid * 16 + g * 4 + r, m = cb * 16 + r16;
      stash[n * 64 + m] = acc[cb][r];
    }
}

// ---------------- K2b: softmax + PV over a d-half (unchanged R9) ----------------
__global__ __launch_bounds__(256) void k_pv(const float* qkv0,
                                            const float* __restrict__ wdw,
                                            const float* __restrict__ temperature,
                                            float* __restrict__ out) {
  __shared__ u16 Ph[64 * PST], Pl[64 * PST];
  __shared__ u16 Vh[64 * PST], Vl[64 * PST];
  __shared__ float invk[64];
  const int t = threadIdx.x;
  const int u = blockIdx.x >> 1, hd = blockIdx.x & 1;
  const int b = u >> 6, ch = u & 63;
  const float* vpl = qkv0 + (((size_t)b * 192 + 128 + ch) << 16);
  const float* sb0 = qkv0 + (((size_t)b * 192 + ch) << 16) + 256;
  const float* sb1 = sb0 + 32768;
  float wv[9];
#pragma unroll
  for (int i = 0; i < 9; ++i) wv[i] = wdw[(128 + ch) * 9 + i];
  const float tscale = temperature[ch >> 3];
  const int wid = t >> 6, g = (t >> 4) & 3, r16 = t & 15;

  if (t < 64) {
    float s = sb0[4096 + 64 + t] + sb1[4096 + 64 + t];
    invk[t] = 1.f / fmaxf(sqrtf(s), 1e-12f);
  }
  __syncthreads();

  const int row = wid * 16 + r16;
  float sq = sb0[4096 + row] + sb1[4096 + row];
  const float invq = 1.f / fmaxf(sqrtf(sq), 1e-12f);
  float sv[16];
  const float* s0r = sb0 + row * 64 + g * 16;
  const float* s1r = sb1 + row * 64 + g * 16;
  float mx = -1e30f;
#pragma unroll
  for (int j = 0; j < 16; ++j) {
    sv[j] = (s0r[j] + s1r[j]) * invq * invk[g * 16 + j] * tscale;
    mx = fmaxf(mx, sv[j]);
  }
  mx = fmaxf(mx, __shfl_xor(mx, 16));
  mx = fmaxf(mx, __shfl_xor(mx, 32));
  float ss = 0.f;
#pragma unroll
  for (int j = 0; j < 16; ++j) {
    sv[j] = __expf(sv[j] - mx);
    ss += sv[j];
  }
  ss += __shfl_xor(ss, 16);
  ss += __shfl_xor(ss, 32);
  const float rs = 1.f / ss;
  short8 h0, h1, l0, l1;
#pragma unroll
  for (int j = 0; j < 8; ++j) {
    u16 h, l;
    fsplit(sv[j] * rs, h, l);
    h0[j] = (short)h; l0[j] = (short)l;
    fsplit(sv[8 + j] * rs, h, l);
    h1[j] = (short)h; l1[j] = (short)l;
  }
  *(short8*)&Ph[row * PST + g * 16] = h0;
  *(short8*)&Ph[row * PST + g * 16 + 8] = h1;
  *(short8*)&Pl[row * PST + g * 16] = l0;
  *(short8*)&Pl[row * PST + g * 16 + 8] = l1;
  __syncthreads();

  short8 pah[2], pal[2];
#pragma unroll
  for (int ks = 0; ks < 2; ++ks) {
    pah[ks] = ldfrag(Ph, wid * 16 + r16, ks * 32 + g * 8);
    pal[ks] = ldfrag(Pl, wid * 16 + r16, ks * 32 + g * 8);
  }

  size_t obase = ((size_t)b * 64 + ch) << 16;
  for (int c8 = 0; c8 < 8; ++c8) {
    const int cd = hd * 8 + c8;
    stage_vt(vpl, wv, Vh, Vl, cd, t);
    __syncthreads();
    f4 po[4];
#pragma unroll
    for (int cb = 0; cb < 4; ++cb)
#pragma unroll
      for (int e = 0; e < 4; ++e) po[cb][e] = 0.f;
#pragma unroll
    for (int ks = 0; ks < 2; ++ks) {
      const int ko = ks * 32 + g * 8;
#pragma unroll
      for (int cb = 0; cb < 4; ++cb) {
        short8 bh = ldfrag(Vh, cb * 16 + r16, ko);
        short8 bl = ldfrag(Vl, cb * 16 + r16, ko);
        po[cb] = __builtin_amdgcn_mfma_f32_16x16x32_bf16(pah[ks], bh, po[cb], 0, 0, 0);
        po[cb] = __builtin_amdgcn_mfma_f32_16x16x32_bf16(pah[ks], bl, po[cb], 0, 0, 0);
        po[cb] = __builtin_amdgcn_mfma_f32_16x16x32_bf16(pal[ks], bh, po[cb], 0, 0, 0);
      }
    }
#pragma unroll
    for (int cb = 0; cb < 4; ++cb)
#pragma unroll
      for (int r = 0; r < 4; ++r) {
        int n = wid * 16 + g * 4 + r;
        int d = cd * 64 + cb * 16 + r16;
        int hh = ((d >> 5) << 3) + (n >> 3);
        int ww = ((d & 31) << 3) + (n & 7);
        out[obase + hh * 256 + ww] = po[cb][r];
      }
    __syncthreads();
  }
}

extern "C" void kernel_launch(void* const* d_in, const int* in_sizes, int n_in,
                              void* d_out, int out_size, void* d_ws,
                              size_t ws_size, hipStream_t stream) {
  const float* x = (const float*)d_in[0];
  const float* wqkv = (const float*)d_in[1];
  const float* wdw = (const float*)d_in[2];
  const float* wproj = (const float*)d_in[3];
  const float* temp = (const float*)d_in[4];
  float* out = (float*)d_out;
  float* qkv0 = (float*)d_ws;  // 402,653,184 bytes (S/sumsq stash inside)

  k_pwm<192><<<2048, 256, 0, stream>>>(x, wqkv, qkv0);
  k_qkt<<<1024, 256, 0, stream>>>(qkv0, wdw);
  k_pv<<<1024, 256, 0, stream>>>(qkv0, wdw, temp, out);
  k_pwm<64><<<2048, 256, 0, stream>>>(out, wproj, out);
}